// Round 1
// baseline (135.184 us; speedup 1.0000x reference)
//
#include <hip/hip_runtime.h>

#define BATCH   16
#define NANCH   25200
#define TPB     1024
#define NWAVES  (TPB / 64)
#define MAXK    50
#define PRETOPK 2048
#define CONF_T  0.25f
#define IOU_T   0.45f
#define NEGV    -1000000000.0f

// One workgroup per batch image. Greedy NMS via repeated argmax over an
// LDS-resident score array. Equivalent to ref: pops candidates in exact
// (score desc, index asc) order, caps at 2048 pops (the ref's PRE_NMS_TOPK
// window), keeps a box iff no earlier-KEPT box has IoU >= 0.45, stops after
// 50 keeps (later keeps cannot appear in the top-50 output and suppressed
// boxes never suppress others).
__global__ __launch_bounds__(TPB, 1) void nms_kernel(const float* __restrict__ x,
                                                     float* __restrict__ out) {
    __shared__ float s_scores[NANCH];
    __shared__ float s_wval[NWAVES];
    __shared__ int   s_widx[NWAVES];
    __shared__ float s_kx1[MAXK], s_ky1[MAXK], s_kx2[MAXK], s_ky2[MAXK], s_karea[MAXK];
    __shared__ int   s_best;
    __shared__ int   s_nkept;

    const int b    = blockIdx.x;
    const int tid  = threadIdx.x;
    const int lane = tid & 63;
    const int wave = tid >> 6;

    const float* __restrict__ xb = x + (size_t)b * NANCH * 6;
    float* __restrict__ ob       = out + (size_t)b * MAXK * 6;

    // Stage thresholded scores into LDS.
    for (int i = tid; i < NANCH; i += TPB) {
        float s = xb[(size_t)i * 6 + 4];
        s_scores[i] = (s > CONF_T) ? s : NEGV;
    }
    if (tid == 0) s_nkept = 0;
    __syncthreads();

    for (int pop = 0; pop < PRETOPK; ++pop) {
        // ---- two-level argmax (score desc, index asc) ----
        float bv = NEGV - 1.0f;
        int   bi = NANCH;
        for (int i = tid; i < NANCH; i += TPB) {
            float s = s_scores[i];
            if (s > bv) { bv = s; bi = i; }   // strict >: earliest index wins within thread
        }
        #pragma unroll
        for (int off = 32; off >= 1; off >>= 1) {
            float ov = __shfl_down(bv, off);
            int   oi = __shfl_down(bi, off);
            if (ov > bv || (ov == bv && oi < bi)) { bv = ov; bi = oi; }
        }
        if (lane == 0) { s_wval[wave] = bv; s_widx[wave] = bi; }
        __syncthreads();
        if (wave == 0) {
            bv = (lane < NWAVES) ? s_wval[lane] : (NEGV - 1.0f);
            bi = (lane < NWAVES) ? s_widx[lane] : NANCH;
            #pragma unroll
            for (int off = 32; off >= 1; off >>= 1) {
                float ov = __shfl_down(bv, off);
                int   oi = __shfl_down(bi, off);
                if (ov > bv || (ov == bv && oi < bi)) { bv = ov; bi = oi; }
            }
            if (lane == 0) {
                // valid iff score survived the conf threshold (ref: top_s > 0.5*NEG)
                s_best = (bv > 0.5f * NEGV) ? bi : -1;
                if (s_best >= 0) s_scores[bi] = NEGV - 1.0f;  // pop it
            }
        }
        __syncthreads();
        const int best = s_best;
        if (best < 0) break;  // no valid candidates remain (uniform across block)

        // ---- IoU vs kept list, wave 0 only (nkept <= 50 <= 64 lanes) ----
        if (wave == 0) {
            const float bx1 = xb[(size_t)best * 6 + 0];
            const float by1 = xb[(size_t)best * 6 + 1];
            const float bx2 = xb[(size_t)best * 6 + 2];
            const float by2 = xb[(size_t)best * 6 + 3];
            const float ba  = fmaxf(bx2 - bx1, 0.0f) * fmaxf(by2 - by1, 0.0f);
            const int   nk  = s_nkept;
            bool sup = false;
            if (lane < nk) {
                float iw = fminf(bx2, s_kx2[lane]) - fmaxf(bx1, s_kx1[lane]);
                float ih = fminf(by2, s_ky2[lane]) - fmaxf(by1, s_ky1[lane]);
                iw = fmaxf(iw, 0.0f);
                ih = fmaxf(ih, 0.0f);
                float inter = iw * ih;
                float uni   = ba + s_karea[lane] - inter;
                float iou   = inter / fmaxf(uni, 1e-9f);
                sup = (iou >= IOU_T);
            }
            unsigned long long m = __ballot(sup);
            if (lane == 0 && m == 0ULL) {
                s_kx1[nk] = bx1; s_ky1[nk] = by1;
                s_kx2[nk] = bx2; s_ky2[nk] = by2;
                s_karea[nk] = ba;
                ob[nk * 6 + 0] = bx1;
                ob[nk * 6 + 1] = by1;
                ob[nk * 6 + 2] = bx2;
                ob[nk * 6 + 3] = by2;
                ob[nk * 6 + 4] = xb[(size_t)best * 6 + 4];
                ob[nk * 6 + 5] = xb[(size_t)best * 6 + 5];
                s_nkept = nk + 1;
            }
        }
        __syncthreads();
        if (s_nkept >= MAXK) break;
    }
    __syncthreads();

    // Fill unproduced rows with -1.0 (ref: invalid rows are all -1).
    const int nk = s_nkept;
    for (int i = tid; i < (MAXK - nk) * 6; i += TPB) {
        ob[nk * 6 + i] = -1.0f;
    }
}

extern "C" void kernel_launch(void* const* d_in, const int* in_sizes, int n_in,
                              void* d_out, int out_size, void* d_ws, size_t ws_size,
                              hipStream_t stream) {
    const float* x = (const float*)d_in[0];
    float* out     = (float*)d_out;
    nms_kernel<<<BATCH, TPB, 0, stream>>>(x, out);
}

// Round 2
// 34.144 us; speedup vs baseline: 3.9592x; 3.9592x over previous
//
#include <hip/hip_runtime.h>

#define BATCH   16
#define NANCH   25200
#define TPB     1024
#define MAXK    50
#define PRETOPK 2048
#define CONF_T  0.25f
#define IOU_T   0.45f
#define NEGV    -1000000000.0f
#define NBINS   4096
#define CHUNK   256   // candidates per round; single-wave in-register sortable

// bin over (0.25, 1.0+]: monotone in s, equal scores -> equal bins
__device__ __forceinline__ int bin_of(float s) {
    int b = (int)((s - CONF_T) * ((float)NBINS / 0.75f));
    return b > (NBINS - 1) ? (NBINS - 1) : b;
}

// One workgroup per batch image.
// Histogram-select top<=256 candidates -> in-register bitonic sort (exact
// (score desc, idx asc) order == lax.top_k tie semantics) -> serial greedy
// NMS on wave 0 with kept boxes one-per-lane. Multi-round over descending
// bin ranges keeps exact equivalence with the ref's top-2048 window.
__global__ __launch_bounds__(TPB, 1) void nms_kernel(const float* __restrict__ x,
                                                     float* __restrict__ out) {
    __shared__ float s_scores[NANCH];                 // 100800 B
    __shared__ unsigned int s_hist[NBINS];            //  16384 B
    __shared__ unsigned long long s_keys[CHUNK];      //   2048 B
    __shared__ float s_rows[CHUNK][6];                //   6144 B
    __shared__ int s_hi, s_c, s_cnt, s_nk, s_P;

    const int b    = blockIdx.x;
    const int tid  = threadIdx.x;
    const int lane = tid & 63;
    const int wave = tid >> 6;

    const float* __restrict__ xb = x + (size_t)b * NANCH * 6;
    float* __restrict__ ob       = out + (size_t)b * MAXK * 6;

    for (int i = tid; i < NBINS; i += TPB) s_hist[i] = 0u;
    if (tid == 0) { s_hi = NBINS; s_nk = 0; s_P = 0; }
    __syncthreads();

    // Pass 1: stage thresholded scores + histogram.
    for (int i = tid; i < NANCH; i += TPB) {
        float s = xb[(size_t)i * 6 + 4];
        bool valid = s > CONF_T;
        s_scores[i] = valid ? s : NEGV;
        if (valid) atomicAdd(&s_hist[bin_of(s)], 1u);
    }
    __syncthreads();

    // Kept boxes live in wave-0 registers, one per lane (nk <= 50 < 64).
    float kx1 = 0.f, ky1 = 0.f, kx2 = 0.f, ky2 = 0.f, ka = 0.f;
    int nk = 0;

    while (s_nk < MAXK && s_P < PRETOPK && s_hi > 0) {
        // ---- wave 0: pick cutoff bin range [c, hi) with count <= CHUNK ----
        if (wave == 0) {
            int c = s_hi;
            int room = CHUNK;
            while (c > 0) {
                int nb = c < 64 ? c : 64;
                unsigned cnt = (lane < nb) ? s_hist[c - 1 - lane] : 0u;  // lane0 = highest bin
                unsigned pre = cnt;
                #pragma unroll
                for (int o = 1; o < 64; o <<= 1) {
                    unsigned t = __shfl_up(pre, o);
                    if (lane >= o) pre += t;
                }
                unsigned total = __shfl(pre, 63);
                if (total <= (unsigned)room) { room -= (int)total; c -= nb; continue; }
                unsigned long long m = __ballot((lane < nb) && (pre <= (unsigned)room));
                int n = __popcll(m);
                if (n == 0 && room == CHUNK) n = 1;  // >CHUNK ties in one bin (pathological)
                c -= n;
                break;
            }
            if (lane == 0) s_c = c;
        } else {
            int z = tid - 64;                    // waves 1..15 zero the staging arrays
            if (z < CHUNK) s_keys[z] = 0ULL;
            if (z == CHUNK) s_cnt = 0;
        }
        __syncthreads();

        const int c = s_c, hi = s_hi;

        // ---- collect candidates in [c, hi): key + full row into LDS ----
        for (int i = tid; i < NANCH; i += TPB) {
            float s = s_scores[i];
            if (s > CONF_T) {
                int bn = bin_of(s);
                if (bn >= c && bn < hi) {
                    int slot = atomicAdd(&s_cnt, 1);
                    if (slot < CHUNK) {
                        // key: [score_bits:32][inv_idx:15][slot:8]  (desc sort ->
                        // score desc, idx asc; pad key 0 sorts last)
                        unsigned long long key =
                            ((unsigned long long)__float_as_uint(s) << 23) |
                            ((unsigned long long)(32767 - i) << 8) |
                            (unsigned long long)slot;
                        s_keys[slot] = key;
                        const float2* rp = (const float2*)(xb + (size_t)i * 6);
                        float2 r0 = rp[0], r1 = rp[1], r2 = rp[2];
                        s_rows[slot][0] = r0.x; s_rows[slot][1] = r0.y;
                        s_rows[slot][2] = r1.x; s_rows[slot][3] = r1.y;
                        s_rows[slot][4] = r2.x; s_rows[slot][5] = r2.y;
                    }
                }
            }
        }
        __syncthreads();

        // ---- wave 0: in-register bitonic sort (256 = 64 lanes x 4 regs) + greedy ----
        if (wave == 0) {
            unsigned long long a[4];
            #pragma unroll
            for (int r = 0; r < 4; ++r) a[r] = s_keys[r * 64 + lane];

            // descending bitonic over virtual index v = r*64 + lane
            #pragma unroll
            for (int k = 2; k <= CHUNK; k <<= 1) {
                #pragma unroll
                for (int j = k >> 1; j > 0; j >>= 1) {
                    if (j >= 64) {
                        const int rj = j >> 6;
                        #pragma unroll
                        for (int r = 0; r < 4; ++r) {
                            if ((r & rj) == 0) {
                                const int rp = r | rj;
                                const int v = r * 64 + lane;
                                bool takeMax = ((v & k) == 0);
                                unsigned long long x0 = a[r], x1 = a[rp];
                                unsigned long long mx = x0 > x1 ? x0 : x1;
                                unsigned long long mn = x0 > x1 ? x1 : x0;
                                a[r]  = takeMax ? mx : mn;
                                a[rp] = takeMax ? mn : mx;
                            }
                        }
                    } else {
                        #pragma unroll
                        for (int r = 0; r < 4; ++r) {
                            const int v = r * 64 + lane;
                            unsigned long long other = __shfl_xor(a[r], j);
                            bool takeMax = (((v & k) == 0) != ((v & j) != 0));
                            unsigned long long mine = a[r];
                            bool gt = mine > other;
                            unsigned long long mx = gt ? mine : other;
                            unsigned long long mn = gt ? other : mine;
                            a[r] = takeMax ? mx : mn;
                        }
                    }
                }
            }

            int K    = s_cnt < CHUNK ? s_cnt : CHUNK;
            int rem  = PRETOPK - s_P;
            int Kproc = K < rem ? K : rem;

            for (int ii = 0; ii < Kproc && nk < MAXK; ++ii) {
                const int rr = ii >> 6;
                unsigned long long sel = rr == 0 ? a[0] : rr == 1 ? a[1] : rr == 2 ? a[2] : a[3];
                unsigned long long key = __shfl(sel, ii & 63);
                const int slot = (int)(key & 0xFFULL);
                const float bx1 = s_rows[slot][0], by1 = s_rows[slot][1];
                const float bx2 = s_rows[slot][2], by2 = s_rows[slot][3];
                const float ba  = fmaxf(bx2 - bx1, 0.0f) * fmaxf(by2 - by1, 0.0f);
                bool sup = false;
                if (lane < nk) {
                    float iw = fmaxf(fminf(bx2, kx2) - fmaxf(bx1, kx1), 0.0f);
                    float ih = fmaxf(fminf(by2, ky2) - fmaxf(by1, ky1), 0.0f);
                    float inter = iw * ih;
                    float uni   = ba + ka - inter;
                    sup = (inter / fmaxf(uni, 1e-9f)) >= IOU_T;
                }
                if (__ballot(sup) == 0ULL) {
                    if (lane == nk) {
                        kx1 = bx1; ky1 = by1; kx2 = bx2; ky2 = by2; ka = ba;
                        ob[nk * 6 + 0] = bx1;
                        ob[nk * 6 + 1] = by1;
                        ob[nk * 6 + 2] = bx2;
                        ob[nk * 6 + 3] = by2;
                        ob[nk * 6 + 4] = s_rows[slot][4];
                        ob[nk * 6 + 5] = s_rows[slot][5];
                    }
                    ++nk;
                }
            }
            if (lane == 0) { s_nk = nk; s_P = s_P + Kproc; s_hi = s_c; }
        }
        __syncthreads();
    }

    // Fill remaining rows with -1.0.
    const int nkf = s_nk;
    for (int i = tid; i < (MAXK - nkf) * 6; i += TPB) {
        ob[nkf * 6 + i] = -1.0f;
    }
}

extern "C" void kernel_launch(void* const* d_in, const int* in_sizes, int n_in,
                              void* d_out, int out_size, void* d_ws, size_t ws_size,
                              hipStream_t stream) {
    const float* x = (const float*)d_in[0];
    float* out     = (float*)d_out;
    nms_kernel<<<BATCH, TPB, 0, stream>>>(x, out);
}